// Round 4
// baseline (552.915 us; speedup 1.0000x reference)
//
#include <hip/hip_runtime.h>

// network_5299989643808: per-(z,zp) tiny MLP over B observations.
// B=2048, Z=64, IDIM=2, HDIM=4, NOPT=4. f32 in / f32 out.
// Outputs concat flat: pi [B,Z,Z,4], log_pi [B,Z,Z,4], xi [B,Z,Z,4].
//
// R4: weights in LDS, lane=zp mapping (coalesced loads AND stores, no
// steady-state barriers).
//  - R0-R2 kept 88 per-lane weight floats in VGPRs -> ~150 VGPR -> 2
//    waves/SIMD, latency-bound at ~156us kernel vs 64us write floor.
//    R3 fixed regs but broke coalescing (stride-256B gathers) + 32 barriers.
//  - block = one z-row x 128 b's. Stage 64 pairs' weights once into LDS,
//    LN affines folded (72 floats/pair, stride 76: rows 16B-aligned,
//    ds_read_b128 start bank 12*zp%32 covers all banks / 8 lanes ->
//    conflict-free). Steady loop: 18 ds_read_b128 per site, ~45 VGPR,
//    __launch_bounds__(512,8) -> 8 waves/SIMD TLP hides the serial chain.
//  - stores: lane=zp -> 3x 1KB full-line segments per wave per site.

#define ZD 64
#define BD 2048
#define NPAIR (ZD * ZD)                 // 4096
#define OFFW ((size_t)BD * NPAIR * 4)   // floats per output tensor
#define WSTRIDE 76                      // 72 used + pad; 304B, 16B-aligned

#define LOG2E 1.4426950408889634f
#define LN2   0.6931471805599453f

__device__ __forceinline__ float fast_exp(float x) {
    return __builtin_amdgcn_exp2f(x * LOG2E);
}

__device__ __forceinline__ float fast_tanh(float x) {
    float y = fminf(fmaxf(x, -9.0f), 9.0f);
    float t = __builtin_amdgcn_exp2f(y * (2.0f * LOG2E));
    return (t - 1.0f) * __builtin_amdgcn_rcpf(t + 1.0f);
}

__device__ __forceinline__ float4 lds4(const float* p) {
    return *reinterpret_cast<const float4*>(p);
}

__global__ __launch_bounds__(512, 8) void net_kernel(
    const float* __restrict__ nt,
    const float* __restrict__ W1,  const float* __restrict__ b1,
    const float* __restrict__ g1,  const float* __restrict__ be1,
    const float* __restrict__ W2,  const float* __restrict__ b2,
    const float* __restrict__ g2,  const float* __restrict__ be2,
    const float* __restrict__ Wpi, const float* __restrict__ bpi,
    const float* __restrict__ Wxi, const float* __restrict__ bxi,
    float* __restrict__ out)
{
    const int tid  = threadIdx.x;
    const int lane = tid & 63;            // zp
    const int wid  = tid >> 6;            // 0..7 -> b sub-range
    const int z    = blockIdx.x >> 4;     // one z-row per block
    const int bs   = blockIdx.x & 15;     // 16 b-slices of 128

    // row layout (stride 76 floats):
    // 0:w1a[4] 4:w1b[4] 8:b1[4] 12:W2f[16](i*4+k) 28:b2f[4]
    // 32:Wpf[16](k*4+o) 48:bpf[4] 52:Wxf[16] 68:bxf[4]
    __shared__ float wlds[ZD * WSTRIDE];  // 19.5 KB

    // ---- stage + fold: 256 threads, 4 per pair ----
    if (tid < 256) {
        const int j = tid >> 2, q = tid & 3;
        const int p = z * ZD + j;
        float* row = &wlds[j * WSTRIDE];
        if (q == 0) {
            #pragma unroll
            for (int i = 0; i < 4; ++i) {
                row[i]     = W1[p * 8 + i];
                row[4 + i] = W1[p * 8 + 4 + i];
                row[8 + i] = b1[p * 4 + i];
            }
        } else if (q == 1) {
            float g[4], be[4];
            #pragma unroll
            for (int i = 0; i < 4; ++i) { g[i] = g1[p*4+i]; be[i] = be1[p*4+i]; }
            #pragma unroll
            for (int k = 0; k < 4; ++k) {
                float acc = b2[p * 4 + k];
                #pragma unroll
                for (int i = 0; i < 4; ++i) {
                    float wv = W2[p * 16 + i * 4 + k];
                    row[12 + i * 4 + k] = g[i] * wv;
                    acc = fmaf(be[i], wv, acc);
                }
                row[28 + k] = acc;
            }
        } else if (q == 2) {
            float g[4], be[4];
            #pragma unroll
            for (int k = 0; k < 4; ++k) { g[k] = g2[p*4+k]; be[k] = be2[p*4+k]; }
            #pragma unroll
            for (int o = 0; o < 4; ++o) {
                float ap = bpi[p * 4 + o];
                #pragma unroll
                for (int k = 0; k < 4; ++k) {
                    float wp = Wpi[p * 16 + k * 4 + o];
                    row[32 + k * 4 + o] = g[k] * wp;
                    ap = fmaf(be[k], wp, ap);
                }
                row[48 + o] = ap;
            }
        } else {
            float g[4], be[4];
            #pragma unroll
            for (int k = 0; k < 4; ++k) { g[k] = g2[p*4+k]; be[k] = be2[p*4+k]; }
            #pragma unroll
            for (int o = 0; o < 4; ++o) {
                float ax = bxi[p * 4 + o];
                #pragma unroll
                for (int k = 0; k < 4; ++k) {
                    float wx = Wxi[p * 16 + k * 4 + o];
                    row[52 + k * 4 + o] = g[k] * wx;
                    ax = fmaf(be[k], wx, ax);
                }
                row[68 + o] = ax;
            }
        }
    }
    __syncthreads();

    // ---- steady loop: 16 sites/thread, no barriers ----
    const float* row = &wlds[lane * WSTRIDE];
    const int bbase = bs * 128 + wid * 16;
    const int p     = z * ZD + lane;

    for (int c = 0; c < 16; ++c) {
        const int b = bbase + c;
        const float x0 = nt[b * ZD + z];     // wave-uniform, one line
        const float x1 = nt[b * ZD + lane];  // coalesced 256B

        // layer 1: 2->4, tanh, LN (affine folded downstream)
        float4 w1a = lds4(row), w1b = lds4(row + 4), b1v = lds4(row + 8);
        float h0 = fast_tanh(fmaf(x0, w1a.x, fmaf(x1, w1b.x, b1v.x)));
        float h1 = fast_tanh(fmaf(x0, w1a.y, fmaf(x1, w1b.y, b1v.y)));
        float h2 = fast_tanh(fmaf(x0, w1a.z, fmaf(x1, w1b.z, b1v.z)));
        float h3 = fast_tanh(fmaf(x0, w1a.w, fmaf(x1, w1b.w, b1v.w)));
        float m  = (h0 + h1 + h2 + h3) * 0.25f;
        float d0 = h0 - m, d1 = h1 - m, d2 = h2 - m, d3 = h3 - m;
        float v  = (d0*d0 + d1*d1 + d2*d2 + d3*d3) * 0.25f;
        float rs = rsqrtf(v + 1e-5f);
        float n0 = d0 * rs, n1 = d1 * rs, n2 = d2 * rs, n3 = d3 * rs;

        // layer 2: 4->4 (g1/be1 folded), tanh, LN
        float4 a = lds4(row + 28);
        float4 wr;
        wr = lds4(row + 12); a.x = fmaf(n0, wr.x, a.x); a.y = fmaf(n0, wr.y, a.y); a.z = fmaf(n0, wr.z, a.z); a.w = fmaf(n0, wr.w, a.w);
        wr = lds4(row + 16); a.x = fmaf(n1, wr.x, a.x); a.y = fmaf(n1, wr.y, a.y); a.z = fmaf(n1, wr.z, a.z); a.w = fmaf(n1, wr.w, a.w);
        wr = lds4(row + 20); a.x = fmaf(n2, wr.x, a.x); a.y = fmaf(n2, wr.y, a.y); a.z = fmaf(n2, wr.z, a.z); a.w = fmaf(n2, wr.w, a.w);
        wr = lds4(row + 24); a.x = fmaf(n3, wr.x, a.x); a.y = fmaf(n3, wr.y, a.y); a.z = fmaf(n3, wr.z, a.z); a.w = fmaf(n3, wr.w, a.w);
        h0 = fast_tanh(a.x); h1 = fast_tanh(a.y); h2 = fast_tanh(a.z); h3 = fast_tanh(a.w);
        m  = (h0 + h1 + h2 + h3) * 0.25f;
        d0 = h0 - m; d1 = h1 - m; d2 = h2 - m; d3 = h3 - m;
        v  = (d0*d0 + d1*d1 + d2*d2 + d3*d3) * 0.25f;
        rs = rsqrtf(v + 1e-5f);
        float u0 = d0 * rs, u1 = d1 * rs, u2 = d2 * rs, u3 = d3 * rs;

        // heads (g2/be2 folded)
        float4 l = lds4(row + 48), q4 = lds4(row + 68);
        wr = lds4(row + 32); l.x = fmaf(u0, wr.x, l.x); l.y = fmaf(u0, wr.y, l.y); l.z = fmaf(u0, wr.z, l.z); l.w = fmaf(u0, wr.w, l.w);
        wr = lds4(row + 36); l.x = fmaf(u1, wr.x, l.x); l.y = fmaf(u1, wr.y, l.y); l.z = fmaf(u1, wr.z, l.z); l.w = fmaf(u1, wr.w, l.w);
        wr = lds4(row + 40); l.x = fmaf(u2, wr.x, l.x); l.y = fmaf(u2, wr.y, l.y); l.z = fmaf(u2, wr.z, l.z); l.w = fmaf(u2, wr.w, l.w);
        wr = lds4(row + 44); l.x = fmaf(u3, wr.x, l.x); l.y = fmaf(u3, wr.y, l.y); l.z = fmaf(u3, wr.z, l.z); l.w = fmaf(u3, wr.w, l.w);
        wr = lds4(row + 52); q4.x = fmaf(u0, wr.x, q4.x); q4.y = fmaf(u0, wr.y, q4.y); q4.z = fmaf(u0, wr.z, q4.z); q4.w = fmaf(u0, wr.w, q4.w);
        wr = lds4(row + 56); q4.x = fmaf(u1, wr.x, q4.x); q4.y = fmaf(u1, wr.y, q4.y); q4.z = fmaf(u1, wr.z, q4.z); q4.w = fmaf(u1, wr.w, q4.w);
        wr = lds4(row + 60); q4.x = fmaf(u2, wr.x, q4.x); q4.y = fmaf(u2, wr.y, q4.y); q4.z = fmaf(u2, wr.z, q4.z); q4.w = fmaf(u2, wr.w, q4.w);
        wr = lds4(row + 64); q4.x = fmaf(u3, wr.x, q4.x); q4.y = fmaf(u3, wr.y, q4.y); q4.z = fmaf(u3, wr.z, q4.z); q4.w = fmaf(u3, wr.w, q4.w);

        // log-softmax / pi / sigmoid
        float mx = fmaxf(fmaxf(l.x, l.y), fmaxf(l.z, l.w));
        float e0 = fast_exp(l.x - mx), e1 = fast_exp(l.y - mx);
        float e2 = fast_exp(l.z - mx), e3 = fast_exp(l.w - mx);
        float s  = e0 + e1 + e2 + e3;
        float inv_s = __builtin_amdgcn_rcpf(s);
        float ls = __builtin_amdgcn_logf(s) * LN2;

        float4 ppi, plp, pxi;
        ppi.x = e0 * inv_s; ppi.y = e1 * inv_s; ppi.z = e2 * inv_s; ppi.w = e3 * inv_s;
        plp.x = (l.x - mx) - ls; plp.y = (l.y - mx) - ls;
        plp.z = (l.z - mx) - ls; plp.w = (l.w - mx) - ls;
        pxi.x = __builtin_amdgcn_rcpf(1.0f + fast_exp(-q4.x));
        pxi.y = __builtin_amdgcn_rcpf(1.0f + fast_exp(-q4.y));
        pxi.z = __builtin_amdgcn_rcpf(1.0f + fast_exp(-q4.z));
        pxi.w = __builtin_amdgcn_rcpf(1.0f + fast_exp(-q4.w));

        const size_t gi = ((size_t)b * NPAIR + p) * 4;   // lane-consecutive 16B
        *reinterpret_cast<float4*>(out + gi)            = ppi;
        *reinterpret_cast<float4*>(out + OFFW + gi)     = plp;
        *reinterpret_cast<float4*>(out + 2 * OFFW + gi) = pxi;
    }
}

extern "C" void kernel_launch(void* const* d_in, const int* in_sizes, int n_in,
                              void* d_out, int out_size, void* d_ws, size_t ws_size,
                              hipStream_t stream) {
    const float* nt  = (const float*)d_in[0];
    const float* W1  = (const float*)d_in[1];
    const float* b1  = (const float*)d_in[2];
    const float* g1  = (const float*)d_in[3];
    const float* be1 = (const float*)d_in[4];
    const float* W2  = (const float*)d_in[5];
    const float* b2  = (const float*)d_in[6];
    const float* g2  = (const float*)d_in[7];
    const float* be2 = (const float*)d_in[8];
    const float* Wpi = (const float*)d_in[9];
    const float* bpi = (const float*)d_in[10];
    const float* Wxi = (const float*)d_in[11];
    const float* bxi = (const float*)d_in[12];
    float* out = (float*)d_out;

    // 64 z-rows x 16 b-slices = 1024 blocks x 512 threads (8 waves)
    dim3 grid(ZD * 16), block(512);
    net_kernel<<<grid, block, 0, stream>>>(nt, W1, b1, g1, be1, W2, b2, g2, be2,
                                           Wpi, bpi, Wxi, bxi, out);
}

// Round 6
// 426.885 us; speedup vs baseline: 1.2952x; 1.2952x over previous
//
#include <hip/hip_runtime.h>

// network_5299989643808: per-(z,zp) tiny MLP over B observations.
// B=2048, Z=64, IDIM=2, HDIM=4, NOPT=4. f32 in / f32 out.
// Outputs concat flat: pi [B,Z,Z,4], log_pi [B,Z,Z,4], xi [B,Z,Z,4].
//
// R5 (resubmit — previous round failed on container acquisition, not the
// kernel): consolidation on the best structure (R1: thread = pair x 16 b's,
// lane=zp, everything coalesced, no LDS, no barriers).
//  - Session evidence: kernel time tracks per-batch issue cycles (R0/R1/R4
//    ratios), i.e. stall-dominated at ~20% utilization; R4's LDS weights
//    were 4-way bank-conflicted (stride 76 -> 8 start banks); R2's
//    launch_bounds pin was neutral because ~150 VGPR forced spills.
//  - Fix: get under 128 VGPR structurally. LN affines folded into W2 and
//    heads (88 -> 72 weight regs, -16 VALU/site; folding HW-verified in
//    R3/R4). Softmax max-subtraction dropped (|logits| <= ~5 << 88
//    overflow bound: LN out |u|<=sqrt(3), weights 0.1*N(0,1)): -11 VALU,
//    shorter serial chain. unroll 1 + pointer-bump stores keep temps ~25.
//    Peak ~110 VGPR -> (256,4) satisfiable with NO spills -> 4 waves/SIMD.

#define ZD 64
#define BD 2048
#define NPAIR (ZD * ZD)                 // 4096
#define BCHUNK 16
#define OFFW ((size_t)BD * NPAIR * 4)   // floats per output tensor

#define LOG2E 1.4426950408889634f
#define LN2   0.6931471805599453f

__device__ __forceinline__ void ld4(const float* __restrict__ p, float* d) {
    float4 v = *reinterpret_cast<const float4*>(p);
    d[0] = v.x; d[1] = v.y; d[2] = v.z; d[3] = v.w;
}

__device__ __forceinline__ float fast_exp(float x) {
    return __builtin_amdgcn_exp2f(x * LOG2E);
}

__device__ __forceinline__ float fast_tanh(float x) {
    float y = fminf(fmaxf(x, -9.0f), 9.0f);
    float t = __builtin_amdgcn_exp2f(y * (2.0f * LOG2E));
    return (t - 1.0f) * __builtin_amdgcn_rcpf(t + 1.0f);
}

__global__ __launch_bounds__(256, 4) void net_kernel(
    const float* __restrict__ nt,
    const float* __restrict__ W1,  const float* __restrict__ b1,
    const float* __restrict__ g1,  const float* __restrict__ be1,
    const float* __restrict__ W2,  const float* __restrict__ b2,
    const float* __restrict__ g2,  const float* __restrict__ be2,
    const float* __restrict__ Wpi, const float* __restrict__ bpi,
    const float* __restrict__ Wxi, const float* __restrict__ bxi,
    float* __restrict__ out)
{
    const int t  = blockIdx.x * 256 + threadIdx.x;
    const int p  = t & (NPAIR - 1);              // lane = zp, z wave-uniform
    const int zp = p & 63;
    const int z  = p >> 6;
    const int b0 = (t >> 12) * BCHUNK;

    // ---- load + fold weights -> 72 registers (once per 16 sites) ----
    float w1a[4], w1b[4], b1v[4];
    ld4(W1 + p * 8,     w1a);
    ld4(W1 + p * 8 + 4, w1b);
    ld4(b1 + p * 4, b1v);

    float W2f[16], b2f[4];
    {
        float g[4], be[4], w[16];
        ld4(g1  + p * 4, g);
        ld4(be1 + p * 4, be);
        #pragma unroll
        for (int i = 0; i < 4; ++i) ld4(W2 + p * 16 + i * 4, w + i * 4);
        ld4(b2 + p * 4, b2f);
        #pragma unroll
        for (int k = 0; k < 4; ++k) {
            #pragma unroll
            for (int i = 0; i < 4; ++i) {
                W2f[i * 4 + k] = g[i] * w[i * 4 + k];
                b2f[k] = fmaf(be[i], w[i * 4 + k], b2f[k]);
            }
        }
    }

    float Wpf[16], bpf[4], Wxf[16], bxf[4];
    {
        float g[4], be[4], wp[16], wx[16];
        ld4(g2  + p * 4, g);
        ld4(be2 + p * 4, be);
        #pragma unroll
        for (int k = 0; k < 4; ++k) {
            ld4(Wpi + p * 16 + k * 4, wp + k * 4);
            ld4(Wxi + p * 16 + k * 4, wx + k * 4);
        }
        ld4(bpi + p * 4, bpf);
        ld4(bxi + p * 4, bxf);
        #pragma unroll
        for (int k = 0; k < 4; ++k) {
            #pragma unroll
            for (int o = 0; o < 4; ++o) {
                Wpf[k * 4 + o] = g[k] * wp[k * 4 + o];
                Wxf[k * 4 + o] = g[k] * wx[k * 4 + o];
                bpf[o] = fmaf(be[k], wp[k * 4 + o], bpf[o]);
                bxf[o] = fmaf(be[k], wx[k * 4 + o], bxf[o]);
            }
        }
    }

    // ---- steady loop: pointer-bump addressing, unroll 1 (cap liveness) ----
    const float* ntp = nt + b0 * ZD;
    float* o_pi = out + ((size_t)b0 * NPAIR + p) * 4;
    float* o_lp = o_pi + OFFW;
    float* o_xi = o_pi + 2 * OFFW;

    #pragma unroll 1
    for (int c = 0; c < BCHUNK; ++c) {
        const float x0 = ntp[z];     // wave-uniform
        const float x1 = ntp[zp];    // coalesced 256B
        ntp += ZD;

        // layer 1: 2->4, tanh, LN (affine folded downstream)
        float h0 = fast_tanh(fmaf(x0, w1a[0], fmaf(x1, w1b[0], b1v[0])));
        float h1 = fast_tanh(fmaf(x0, w1a[1], fmaf(x1, w1b[1], b1v[1])));
        float h2 = fast_tanh(fmaf(x0, w1a[2], fmaf(x1, w1b[2], b1v[2])));
        float h3 = fast_tanh(fmaf(x0, w1a[3], fmaf(x1, w1b[3], b1v[3])));
        float m  = (h0 + h1 + h2 + h3) * 0.25f;
        float d0 = h0 - m, d1 = h1 - m, d2 = h2 - m, d3 = h3 - m;
        float v  = (d0*d0 + d1*d1 + d2*d2 + d3*d3) * 0.25f;
        float rs = rsqrtf(v + 1e-5f);
        float n0 = d0 * rs, n1 = d1 * rs, n2 = d2 * rs, n3 = d3 * rs;

        // layer 2: 4->4 (g1/be1 folded), tanh, LN
        float a0 = b2f[0], a1 = b2f[1], a2 = b2f[2], a3 = b2f[3];
        a0 = fmaf(n0, W2f[0],  a0); a1 = fmaf(n0, W2f[1],  a1); a2 = fmaf(n0, W2f[2],  a2); a3 = fmaf(n0, W2f[3],  a3);
        a0 = fmaf(n1, W2f[4],  a0); a1 = fmaf(n1, W2f[5],  a1); a2 = fmaf(n1, W2f[6],  a2); a3 = fmaf(n1, W2f[7],  a3);
        a0 = fmaf(n2, W2f[8],  a0); a1 = fmaf(n2, W2f[9],  a1); a2 = fmaf(n2, W2f[10], a2); a3 = fmaf(n2, W2f[11], a3);
        a0 = fmaf(n3, W2f[12], a0); a1 = fmaf(n3, W2f[13], a1); a2 = fmaf(n3, W2f[14], a2); a3 = fmaf(n3, W2f[15], a3);
        h0 = fast_tanh(a0); h1 = fast_tanh(a1); h2 = fast_tanh(a2); h3 = fast_tanh(a3);
        m  = (h0 + h1 + h2 + h3) * 0.25f;
        d0 = h0 - m; d1 = h1 - m; d2 = h2 - m; d3 = h3 - m;
        v  = (d0*d0 + d1*d1 + d2*d2 + d3*d3) * 0.25f;
        rs = rsqrtf(v + 1e-5f);
        float u0 = d0 * rs, u1 = d1 * rs, u2 = d2 * rs, u3 = d3 * rs;

        // heads (g2/be2 folded)
        float l0 = bpf[0], l1 = bpf[1], l2 = bpf[2], l3 = bpf[3];
        float q0 = bxf[0], q1 = bxf[1], q2 = bxf[2], q3 = bxf[3];
        l0 = fmaf(u0, Wpf[0],  l0); l1 = fmaf(u0, Wpf[1],  l1); l2 = fmaf(u0, Wpf[2],  l2); l3 = fmaf(u0, Wpf[3],  l3);
        l0 = fmaf(u1, Wpf[4],  l0); l1 = fmaf(u1, Wpf[5],  l1); l2 = fmaf(u1, Wpf[6],  l2); l3 = fmaf(u1, Wpf[7],  l3);
        l0 = fmaf(u2, Wpf[8],  l0); l1 = fmaf(u2, Wpf[9],  l1); l2 = fmaf(u2, Wpf[10], l2); l3 = fmaf(u2, Wpf[11], l3);
        l0 = fmaf(u3, Wpf[12], l0); l1 = fmaf(u3, Wpf[13], l1); l2 = fmaf(u3, Wpf[14], l2); l3 = fmaf(u3, Wpf[15], l3);
        q0 = fmaf(u0, Wxf[0],  q0); q1 = fmaf(u0, Wxf[1],  q1); q2 = fmaf(u0, Wxf[2],  q2); q3 = fmaf(u0, Wxf[3],  q3);
        q0 = fmaf(u1, Wxf[4],  q0); q1 = fmaf(u1, Wxf[5],  q1); q2 = fmaf(u1, Wxf[6],  q2); q3 = fmaf(u1, Wxf[7],  q3);
        q0 = fmaf(u2, Wxf[8],  q0); q1 = fmaf(u2, Wxf[9],  q1); q2 = fmaf(u2, Wxf[10], q2); q3 = fmaf(u2, Wxf[11], q3);
        q0 = fmaf(u3, Wxf[12], q0); q1 = fmaf(u3, Wxf[13], q1); q2 = fmaf(u3, Wxf[14], q2); q3 = fmaf(u3, Wxf[15], q3);

        // softmax without max-subtraction (|l| <= ~5, exp2 safe) + sigmoid
        float e0 = fast_exp(l0), e1 = fast_exp(l1);
        float e2 = fast_exp(l2), e3 = fast_exp(l3);
        float s  = (e0 + e1) + (e2 + e3);
        float inv_s = __builtin_amdgcn_rcpf(s);
        float ls = __builtin_amdgcn_logf(s) * LN2;   // ln(s)

        float4 ppi, plp, pxi;
        ppi.x = e0 * inv_s; ppi.y = e1 * inv_s; ppi.z = e2 * inv_s; ppi.w = e3 * inv_s;
        plp.x = l0 - ls; plp.y = l1 - ls; plp.z = l2 - ls; plp.w = l3 - ls;
        pxi.x = __builtin_amdgcn_rcpf(1.0f + fast_exp(-q0));
        pxi.y = __builtin_amdgcn_rcpf(1.0f + fast_exp(-q1));
        pxi.z = __builtin_amdgcn_rcpf(1.0f + fast_exp(-q2));
        pxi.w = __builtin_amdgcn_rcpf(1.0f + fast_exp(-q3));

        *reinterpret_cast<float4*>(o_pi) = ppi;
        *reinterpret_cast<float4*>(o_lp) = plp;
        *reinterpret_cast<float4*>(o_xi) = pxi;
        o_pi += NPAIR * 4; o_lp += NPAIR * 4; o_xi += NPAIR * 4;
    }
}

extern "C" void kernel_launch(void* const* d_in, const int* in_sizes, int n_in,
                              void* d_out, int out_size, void* d_ws, size_t ws_size,
                              hipStream_t stream) {
    const float* nt  = (const float*)d_in[0];
    const float* W1  = (const float*)d_in[1];
    const float* b1  = (const float*)d_in[2];
    const float* g1  = (const float*)d_in[3];
    const float* be1 = (const float*)d_in[4];
    const float* W2  = (const float*)d_in[5];
    const float* b2  = (const float*)d_in[6];
    const float* g2  = (const float*)d_in[7];
    const float* be2 = (const float*)d_in[8];
    const float* Wpi = (const float*)d_in[9];
    const float* bpi = (const float*)d_in[10];
    const float* Wxi = (const float*)d_in[11];
    const float* bxi = (const float*)d_in[12];
    float* out = (float*)d_out;

    const int total = NPAIR * (BD / BCHUNK);   // 524,288 threads
    dim3 grid(total / 256), block(256);
    net_kernel<<<grid, block, 0, stream>>>(nt, W1, b1, g1, be1, W2, b2, g2, be2,
                                           Wpi, bpi, Wxi, bxi, out);
}

// Round 7
// 423.087 us; speedup vs baseline: 1.3069x; 1.0090x over previous
//
#include <hip/hip_runtime.h>

// network_5299989643808: per-(z,zp) tiny MLP over B observations.
// B=2048, Z=64, IDIM=2, HDIM=4, NOPT=4. f32 in / f32 out.
// Outputs concat flat: pi [B,Z,Z,4], log_pi [B,Z,Z,4], xi [B,Z,Z,4].
//
// R6: attack the STALLS, not the instruction count.
//  Session evidence: R5 (fewer VALU, fewer regs, folded) was SLOWER than R1
//  (156 vs 171 us kernel) -> compute/registers are not the lever. Issue
//  model: ~30us issue + ~65us write floor vs ~171us measured => ~80% stall.
//  Un-modeled actor: 402 MB of streaming stores thrash the 32MB L2 every
//  launch, evicting nt (re-read 64x) and weights (re-read 128x) -> per-site
//  x1 loads become ~900-cyc HBM misses that ~3 resident waves cannot hide.
//  Fix: __builtin_nontemporal_store for all outputs (global_store_dwordx4
//  nt flag, no L2 allocation) keeps nt+weights L2-hot; depth-1 software
//  prefetch of next x0/x1 overlaps the remaining L2 latency. Keep R5's
//  folded weights + max-free softmax; restore R1's unroll 2; no min-waves
//  pin (R2/R5: neutral-to-harmful).

#define ZD 64
#define BD 2048
#define NPAIR (ZD * ZD)                 // 4096
#define BCHUNK 16
#define OFFW ((size_t)BD * NPAIR * 4)   // floats per output tensor

#define LOG2E 1.4426950408889634f
#define LN2   0.6931471805599453f

typedef float v4f __attribute__((ext_vector_type(4)));

__device__ __forceinline__ void ld4(const float* __restrict__ p, float* d) {
    float4 v = *reinterpret_cast<const float4*>(p);
    d[0] = v.x; d[1] = v.y; d[2] = v.z; d[3] = v.w;
}

__device__ __forceinline__ void st4_nt(float* p, float a, float b, float c, float d) {
    v4f v = {a, b, c, d};
    __builtin_nontemporal_store(v, reinterpret_cast<v4f*>(p));
}

__device__ __forceinline__ float fast_exp(float x) {
    return __builtin_amdgcn_exp2f(x * LOG2E);
}

__device__ __forceinline__ float fast_tanh(float x) {
    float y = fminf(fmaxf(x, -9.0f), 9.0f);
    float t = __builtin_amdgcn_exp2f(y * (2.0f * LOG2E));
    return (t - 1.0f) * __builtin_amdgcn_rcpf(t + 1.0f);
}

__global__ __launch_bounds__(256) void net_kernel(
    const float* __restrict__ nt,
    const float* __restrict__ W1,  const float* __restrict__ b1,
    const float* __restrict__ g1,  const float* __restrict__ be1,
    const float* __restrict__ W2,  const float* __restrict__ b2,
    const float* __restrict__ g2,  const float* __restrict__ be2,
    const float* __restrict__ Wpi, const float* __restrict__ bpi,
    const float* __restrict__ Wxi, const float* __restrict__ bxi,
    float* __restrict__ out)
{
    const int t  = blockIdx.x * 256 + threadIdx.x;
    const int p  = t & (NPAIR - 1);              // lane = zp, z wave-uniform
    const int zp = p & 63;
    const int z  = p >> 6;
    const int b0 = (t >> 12) * BCHUNK;

    // ---- load + fold weights -> 72 registers (once per 16 sites) ----
    float w1a[4], w1b[4], b1v[4];
    ld4(W1 + p * 8,     w1a);
    ld4(W1 + p * 8 + 4, w1b);
    ld4(b1 + p * 4, b1v);

    float W2f[16], b2f[4];
    {
        float g[4], be[4], w[16];
        ld4(g1  + p * 4, g);
        ld4(be1 + p * 4, be);
        #pragma unroll
        for (int i = 0; i < 4; ++i) ld4(W2 + p * 16 + i * 4, w + i * 4);
        ld4(b2 + p * 4, b2f);
        #pragma unroll
        for (int k = 0; k < 4; ++k) {
            #pragma unroll
            for (int i = 0; i < 4; ++i) {
                W2f[i * 4 + k] = g[i] * w[i * 4 + k];
                b2f[k] = fmaf(be[i], w[i * 4 + k], b2f[k]);
            }
        }
    }

    float Wpf[16], bpf[4], Wxf[16], bxf[4];
    {
        float g[4], be[4], wp[16], wx[16];
        ld4(g2  + p * 4, g);
        ld4(be2 + p * 4, be);
        #pragma unroll
        for (int k = 0; k < 4; ++k) {
            ld4(Wpi + p * 16 + k * 4, wp + k * 4);
            ld4(Wxi + p * 16 + k * 4, wx + k * 4);
        }
        ld4(bpi + p * 4, bpf);
        ld4(bxi + p * 4, bxf);
        #pragma unroll
        for (int k = 0; k < 4; ++k) {
            #pragma unroll
            for (int o = 0; o < 4; ++o) {
                Wpf[k * 4 + o] = g[k] * wp[k * 4 + o];
                Wxf[k * 4 + o] = g[k] * wx[k * 4 + o];
                bpf[o] = fmaf(be[k], wp[k * 4 + o], bpf[o]);
                bxf[o] = fmaf(be[k], wx[k * 4 + o], bxf[o]);
            }
        }
    }

    // ---- steady loop: depth-1 prefetch of x0/x1, nontemporal stores ----
    const float* ntp = nt + b0 * ZD;
    float* o_pi = out + ((size_t)b0 * NPAIR + p) * 4;
    float* o_lp = o_pi + OFFW;
    float* o_xi = o_pi + 2 * OFFW;

    float x0 = ntp[z];     // wave-uniform
    float x1 = ntp[zp];    // coalesced 256B (L2-hot once stores bypass L2)

    #pragma unroll 2
    for (int c = 0; c < BCHUNK; ++c) {
        // prefetch next site's inputs (clamped on last iter) -- overlaps
        // the ~200cy L2 hit under this site's ~550cy of compute
        const float* nxt = ntp + (c < BCHUNK - 1 ? ZD : 0);
        float nx0 = nxt[z];
        float nx1 = nxt[zp];
        ntp += ZD;

        // layer 1: 2->4, tanh, LN (affine folded downstream)
        float h0 = fast_tanh(fmaf(x0, w1a[0], fmaf(x1, w1b[0], b1v[0])));
        float h1 = fast_tanh(fmaf(x0, w1a[1], fmaf(x1, w1b[1], b1v[1])));
        float h2 = fast_tanh(fmaf(x0, w1a[2], fmaf(x1, w1b[2], b1v[2])));
        float h3 = fast_tanh(fmaf(x0, w1a[3], fmaf(x1, w1b[3], b1v[3])));
        float m  = (h0 + h1 + h2 + h3) * 0.25f;
        float d0 = h0 - m, d1 = h1 - m, d2 = h2 - m, d3 = h3 - m;
        float v  = (d0*d0 + d1*d1 + d2*d2 + d3*d3) * 0.25f;
        float rs = rsqrtf(v + 1e-5f);
        float n0 = d0 * rs, n1 = d1 * rs, n2 = d2 * rs, n3 = d3 * rs;

        // layer 2: 4->4 (g1/be1 folded), tanh, LN
        float a0 = b2f[0], a1 = b2f[1], a2 = b2f[2], a3 = b2f[3];
        a0 = fmaf(n0, W2f[0],  a0); a1 = fmaf(n0, W2f[1],  a1); a2 = fmaf(n0, W2f[2],  a2); a3 = fmaf(n0, W2f[3],  a3);
        a0 = fmaf(n1, W2f[4],  a0); a1 = fmaf(n1, W2f[5],  a1); a2 = fmaf(n1, W2f[6],  a2); a3 = fmaf(n1, W2f[7],  a3);
        a0 = fmaf(n2, W2f[8],  a0); a1 = fmaf(n2, W2f[9],  a1); a2 = fmaf(n2, W2f[10], a2); a3 = fmaf(n2, W2f[11], a3);
        a0 = fmaf(n3, W2f[12], a0); a1 = fmaf(n3, W2f[13], a1); a2 = fmaf(n3, W2f[14], a2); a3 = fmaf(n3, W2f[15], a3);
        h0 = fast_tanh(a0); h1 = fast_tanh(a1); h2 = fast_tanh(a2); h3 = fast_tanh(a3);
        m  = (h0 + h1 + h2 + h3) * 0.25f;
        d0 = h0 - m; d1 = h1 - m; d2 = h2 - m; d3 = h3 - m;
        v  = (d0*d0 + d1*d1 + d2*d2 + d3*d3) * 0.25f;
        rs = rsqrtf(v + 1e-5f);
        float u0 = d0 * rs, u1 = d1 * rs, u2 = d2 * rs, u3 = d3 * rs;

        // heads (g2/be2 folded)
        float l0 = bpf[0], l1 = bpf[1], l2 = bpf[2], l3 = bpf[3];
        float q0 = bxf[0], q1 = bxf[1], q2 = bxf[2], q3 = bxf[3];
        l0 = fmaf(u0, Wpf[0],  l0); l1 = fmaf(u0, Wpf[1],  l1); l2 = fmaf(u0, Wpf[2],  l2); l3 = fmaf(u0, Wpf[3],  l3);
        l0 = fmaf(u1, Wpf[4],  l0); l1 = fmaf(u1, Wpf[5],  l1); l2 = fmaf(u1, Wpf[6],  l2); l3 = fmaf(u1, Wpf[7],  l3);
        l0 = fmaf(u2, Wpf[8],  l0); l1 = fmaf(u2, Wpf[9],  l1); l2 = fmaf(u2, Wpf[10], l2); l3 = fmaf(u2, Wpf[11], l3);
        l0 = fmaf(u3, Wpf[12], l0); l1 = fmaf(u3, Wpf[13], l1); l2 = fmaf(u3, Wpf[14], l2); l3 = fmaf(u3, Wpf[15], l3);
        q0 = fmaf(u0, Wxf[0],  q0); q1 = fmaf(u0, Wxf[1],  q1); q2 = fmaf(u0, Wxf[2],  q2); q3 = fmaf(u0, Wxf[3],  q3);
        q0 = fmaf(u1, Wxf[4],  q0); q1 = fmaf(u1, Wxf[5],  q1); q2 = fmaf(u1, Wxf[6],  q2); q3 = fmaf(u1, Wxf[7],  q3);
        q0 = fmaf(u2, Wxf[8],  q0); q1 = fmaf(u2, Wxf[9],  q1); q2 = fmaf(u2, Wxf[10], q2); q3 = fmaf(u2, Wxf[11], q3);
        q0 = fmaf(u3, Wxf[12], q0); q1 = fmaf(u3, Wxf[13], q1); q2 = fmaf(u3, Wxf[14], q2); q3 = fmaf(u3, Wxf[15], q3);

        // softmax without max-subtraction (|l| <= ~5, exp2 safe) + sigmoid
        float e0 = fast_exp(l0), e1 = fast_exp(l1);
        float e2 = fast_exp(l2), e3 = fast_exp(l3);
        float s  = (e0 + e1) + (e2 + e3);
        float inv_s = __builtin_amdgcn_rcpf(s);
        float ls = __builtin_amdgcn_logf(s) * LN2;   // ln(s)

        // nontemporal: stream to HBM, don't allocate in L2
        st4_nt(o_pi, e0 * inv_s, e1 * inv_s, e2 * inv_s, e3 * inv_s);
        st4_nt(o_lp, l0 - ls, l1 - ls, l2 - ls, l3 - ls);
        st4_nt(o_xi,
               __builtin_amdgcn_rcpf(1.0f + fast_exp(-q0)),
               __builtin_amdgcn_rcpf(1.0f + fast_exp(-q1)),
               __builtin_amdgcn_rcpf(1.0f + fast_exp(-q2)),
               __builtin_amdgcn_rcpf(1.0f + fast_exp(-q3)));
        o_pi += NPAIR * 4; o_lp += NPAIR * 4; o_xi += NPAIR * 4;

        x0 = nx0; x1 = nx1;
    }
}

extern "C" void kernel_launch(void* const* d_in, const int* in_sizes, int n_in,
                              void* d_out, int out_size, void* d_ws, size_t ws_size,
                              hipStream_t stream) {
    const float* nt  = (const float*)d_in[0];
    const float* W1  = (const float*)d_in[1];
    const float* b1  = (const float*)d_in[2];
    const float* g1  = (const float*)d_in[3];
    const float* be1 = (const float*)d_in[4];
    const float* W2  = (const float*)d_in[5];
    const float* b2  = (const float*)d_in[6];
    const float* g2  = (const float*)d_in[7];
    const float* be2 = (const float*)d_in[8];
    const float* Wpi = (const float*)d_in[9];
    const float* bpi = (const float*)d_in[10];
    const float* Wxi = (const float*)d_in[11];
    const float* bxi = (const float*)d_in[12];
    float* out = (float*)d_out;

    const int total = NPAIR * (BD / BCHUNK);   // 524,288 threads
    dim3 grid(total / 256), block(256);
    net_kernel<<<grid, block, 0, stream>>>(nt, W1, b1, g1, be1, W2, b2, g2, be2,
                                           Wpi, bpi, Wxi, bxi, out);
}